// Round 5
// baseline (455.731 us; speedup 1.0000x reference)
//
#include <hip/hip_runtime.h>
#include <math.h>

// Sparsemax over rows of a (16384 x 4096) float32 matrix.
//
// Bound: tau >= max(x) - 1, so the support lies in {x : x > max - 1}
// (typically ~14, tail ~60 candidates for N(0,1) rows). Output is EXACTLY
// zero outside the candidate set.
//
// Persistent pipelined design, one wave per row, grid-stride over rows:
//   iter r: issue loads(r) -> issue zero-fill stores(r) ->
//           solve+fixup row r-1 (LDS-broadcast rank formula; overlaps the
//           in-flight loads of row r) -> max+gather row r (ballot+mbcnt
//           compaction into this wave's LDS segment, no atomics).
// No __syncthreads anywhere; no manual waitcnt (same-wave same-address
// store ordering is HW-guaranteed; compiler handles LDS/load deps).
// Exact tau via rank formula in raw space (max-shift cancels algebraically):
//   C_i = #{j: y_j >= y_i}, S_i = sum{y_j >= y_i};
//   k = max C_i over lanes with 1 + C_i*y_i > S_i; tau = (S_i-1)/C_i.
// Fallback (cnt > 128, ~1 row in 16384): immediate in-register Michelot.

constexpr int N_COLS = 4096;
constexpr int BLOCK = 256;
constexpr int WAVES = BLOCK / 64;        // 4
constexpr int CHUNKS = N_COLS / 4 / 64;  // 16 float4 per lane per row
constexpr int CAP = 128;                 // candidate capacity (2 slots/lane)
constexpr int GRID = 1024;               // 4096 waves -> 4 rows per wave

__global__ __launch_bounds__(BLOCK) void sparsemax_kernel(
    const float* __restrict__ x, float* __restrict__ out, int nrows) {
  const int w = threadIdx.x >> 6;
  const int lane = threadIdx.x & 63;
  const int gw = blockIdx.x * WAVES + w;
  const int nwaves = GRID * WAVES;

  __shared__ float sY[WAVES][CAP];
  __shared__ int sP[WAVES][CAP];
  float* ldsY = sY[w];
  int* ldsP = sP[w];

  // Solve tau for the candidate set currently in this wave's LDS segment and
  // fix up the (already zero-filled) output row. cnt is wave-uniform.
  auto solve_fix = [&](int cnt, float* outr_prev) {
    const bool in0 = lane < cnt, in1 = lane + 64 < cnt;
    float y0 = 0.f, y1 = 0.f;
    int p0 = 0, p1 = 0;
    if (in0) { y0 = ldsY[lane]; p0 = ldsP[lane]; }
    if (in1) { y1 = ldsY[lane + 64]; p1 = ldsP[lane + 64]; }
    float S0 = 0.f, C0 = 0.f, S1 = 0.f, C1 = 0.f;
    for (int j = 0; j < cnt; ++j) {  // uniform trip; ldsY[j] is a broadcast
      float yj = ldsY[j];
      if (yj >= y0) { S0 += yj; C0 += 1.f; }
      if (yj >= y1) { S1 += yj; C1 += 1.f; }
    }
    bool ok0 = in0 && (1.f + C0 * y0 > S0);
    bool ok1 = in1 && (1.f + C1 * y1 > S1);
    float bc = ok0 ? C0 : 0.f;
    float bt = ok0 ? (S0 - 1.f) / C0 : 0.f;
    if (ok1 && C1 > bc) { bc = C1; bt = (S1 - 1.f) / C1; }
#pragma unroll
    for (int off = 32; off >= 1; off >>= 1) {
      float oc = __shfl_xor(bc, off, 64);
      float ot = __shfl_xor(bt, off, 64);
      if (oc > bc) { bc = oc; bt = ot; }
    }
    const float tau = bt;  // uniform (k = max C is unique)
    if (in0) outr_prev[p0] = fmaxf(y0 - tau, 0.f);
    if (in1) outr_prev[p1] = fmaxf(y1 - tau, 0.f);
  };

  int pcnt = 0;           // pipeline state: previous row's candidate count
  float* pout = nullptr;  // previous row's output pointer

  for (int row = gw; row < nrows; row += nwaves) {
    const float4* x4 = (const float4*)(x + (size_t)row * N_COLS);
    float* outr = out + (size_t)row * N_COLS;
    float4* o4 = (float4*)outr;

    // ---- issue this row's loads (16 KB/wave in flight) ----
    float4 f[CHUNKS];
#pragma unroll
    for (int k = 0; k < CHUNKS; ++k) f[k] = x4[k * 64 + lane];

    // ---- zero-fill this row's output now; fixed up next iteration ----
    const float4 z = make_float4(0.f, 0.f, 0.f, 0.f);
#pragma unroll
    for (int k = 0; k < CHUNKS; ++k) o4[k * 64 + lane] = z;

    // ---- solve + fix up PREVIOUS row; overlaps this row's load latency ----
    if (pcnt > 0) solve_fix(pcnt, pout);

    // ---- wave max of this row (first consumption of f) ----
    float m = fmaxf(fmaxf(f[0].x, f[0].y), fmaxf(f[0].z, f[0].w));
#pragma unroll
    for (int k = 1; k < CHUNKS; ++k)
      m = fmaxf(m, fmaxf(fmaxf(f[k].x, f[k].y), fmaxf(f[k].z, f[k].w)));
#pragma unroll
    for (int off = 32; off >= 1; off >>= 1)
      m = fmaxf(m, __shfl_xor(m, off, 64));
    const float thresh = m - 1.0f;

    // ---- gather candidates via ballot + mbcnt compaction (no atomics) ----
    int cnt = 0;
    auto emit = [&](float val, int pos) {
      unsigned long long b = __ballot(val > thresh);
      if (val > thresh) {
        int my = cnt + __builtin_amdgcn_mbcnt_hi(
                           (unsigned)(b >> 32),
                           __builtin_amdgcn_mbcnt_lo((unsigned)b, 0));
        if (my < CAP) { ldsY[my] = val; ldsP[my] = pos; }
      }
      cnt += __popcll(b);  // uniform
    };
#pragma unroll
    for (int k = 0; k < CHUNKS; ++k) {
      const int base = (k * 64 + lane) * 4;
      emit(f[k].x, base + 0);
      emit(f[k].y, base + 1);
      emit(f[k].z, base + 2);
      emit(f[k].w, base + 3);
    }

    if (cnt <= CAP) {
      pcnt = cnt;  // hand this row to the pipeline
      pout = outr;
    } else {
      // ---- fallback (~1 row in 16384): immediate in-register Michelot ----
      float tau = thresh;  // active = {f > m-1}, a support superset
      int prev = -1;
      for (int it = 0; it < 32; ++it) {
        float S = 0.f, C = 0.f;
#pragma unroll
        for (int k = 0; k < CHUNKS; ++k) {
          if (f[k].x > tau) { S += f[k].x; C += 1.f; }
          if (f[k].y > tau) { S += f[k].y; C += 1.f; }
          if (f[k].z > tau) { S += f[k].z; C += 1.f; }
          if (f[k].w > tau) { S += f[k].w; C += 1.f; }
        }
#pragma unroll
        for (int off = 32; off >= 1; off >>= 1) {
          S += __shfl_xor(S, off, 64);
          C += __shfl_xor(C, off, 64);
        }
        int ci = (int)C;
        tau = (S - 1.f) / C;
        if (ci == prev) break;
        prev = ci;
      }
#pragma unroll
      for (int k = 0; k < CHUNKS; ++k) {  // overwrites the zero-fill
        float4 r;
        r.x = fmaxf(f[k].x - tau, 0.f);
        r.y = fmaxf(f[k].y - tau, 0.f);
        r.z = fmaxf(f[k].z - tau, 0.f);
        r.w = fmaxf(f[k].w - tau, 0.f);
        o4[k * 64 + lane] = r;
      }
      pcnt = 0;  // this row is fully handled
    }
  }

  // ---- epilogue: solve + fix up the last pipelined row ----
  if (pcnt > 0) solve_fix(pcnt, pout);
}

extern "C" void kernel_launch(void* const* d_in, const int* in_sizes, int n_in,
                              void* d_out, int out_size, void* d_ws,
                              size_t ws_size, hipStream_t stream) {
  const float* x = (const float*)d_in[0];
  float* out = (float*)d_out;
  const int rows = in_sizes[0] / N_COLS;  // 16384
  sparsemax_kernel<<<GRID, BLOCK, 0, stream>>>(x, out, rows);
}